// Round 1
// baseline (714.900 us; speedup 1.0000x reference)
//
#include <hip/hip_runtime.h>

// Problem dims (fixed).
#define BB 512
#define TT 1024
#define DD 64
#define HH 64
#define G4 256          // 4*H gates
#define RR 4
#define MHH 32
#define BT (BB * TT)    // 524288
#define Y_SIZE (BB * TT * HH)  // 33554432

typedef _Float16 half8 __attribute__((ext_vector_type(8)));
typedef _Float16 half4 __attribute__((ext_vector_type(4)));
typedef float f32x4 __attribute__((ext_vector_type(4)));

#define MFMA16(a, b, c) __builtin_amdgcn_mfma_f32_16x16x32_f16((a), (b), (c), 0, 0, 0)

// sigmoid(x) = 1/(1+e^-x); stable at both ends (exp->inf => rcp->0).
__device__ __forceinline__ float sigm(float x) {
    return __builtin_amdgcn_rcpf(1.0f + __expf(-x));
}
// tanh(x) = 1 - 2/(1+e^{2x}); stable at both ends.
__device__ __forceinline__ float tanh_(float x) {
    return 1.0f - 2.0f * __builtin_amdgcn_rcpf(1.0f + __expf(2.0f * x));
}

__device__ __forceinline__ half8 cvt8(f32x4 a, f32x4 b) {
    half8 h;
    h[0] = (_Float16)a[0]; h[1] = (_Float16)a[1];
    h[2] = (_Float16)a[2]; h[3] = (_Float16)a[3];
    h[4] = (_Float16)b[0]; h[5] = (_Float16)b[1];
    h[6] = (_Float16)b[2]; h[7] = (_Float16)b[3];
    return h;
}

// ---------------------------------------------------------------------------
// LSTM kernel: 512 WGs (ONE batch row each), 256 threads (4 waves).
// vs previous 256-WG/2-row version: 2 independent WGs per CU (2 waves/SIMD
// from unsynchronized streams) so one WG's latency chain (LDS read -> MFMA
// chain -> transcendental activation -> LDS write -> barrier) is hidden under
// the other's issue. A-matrix rows are the SAME batch row replicated 16x, so
// D reg0 of every lane holds gate (col = lane&15); quad 0 is the writer.
// Bias is fed as the MFMA C operand (no per-step acc re-init movs).
// h double-buffered in LDS => ONE barrier per step.
// ---------------------------------------------------------------------------
__global__ __launch_bounds__(256) void lstm_kernel(
    const float* __restrict__ x, const float* __restrict__ h_init,
    const float* __restrict__ c_init, const float* __restrict__ W_ih,
    const float* __restrict__ W_hh, const float* __restrict__ b_ih,
    const float* __restrict__ b_hh, float* __restrict__ y)
{
    __shared__ alignas(16) _Float16 xch[2][16][DD];  // x chunks, f16, dbuf
    __shared__ alignas(16) _Float16 hst[2][HH];      // h stage, dbuf

    const int tid  = threadIdx.x;
    const int wave = tid >> 6;
    const int lane = tid & 63;
    const int col  = lane & 15;
    const int quad = lane >> 4;
    const int j    = (wave << 4) + col;     // hidden unit index [0,64)
    const bool writer = (quad == 0);        // quads 1..3 are duplicates

    const int b = blockIdx.x;

    // ---- resident weight fragments: B[k][n] = Wcat[n][k] (f16) ----
    // n = 64*G + j ; k chunks: 0,1 -> W_ih, 2,3 -> W_hh
    half8 bf[4][4];
    f32x4 biasv[4];
#pragma unroll
    for (int G = 0; G < 4; ++G) {
        const int n = (G << 6) + j;
        const float bs = b_ih[n] + b_hh[n];
        biasv[G][0] = bs; biasv[G][1] = bs; biasv[G][2] = bs; biasv[G][3] = bs;
#pragma unroll
        for (int c = 0; c < 4; ++c) {
            const float* src = (c < 2) ? (W_ih + n * DD + c * 32 + quad * 8)
                                       : (W_hh + n * HH + (c - 2) * 32 + quad * 8);
            f32x4 w0 = *(const f32x4*)src;
            f32x4 w1 = *(const f32x4*)(src + 4);
            bf[G][c] = cvt8(w0, w1);
        }
    }

    float c_state = c_init[j];

    // ---- init h stage (buffer 0) + first x chunk ----
    if (tid < HH) hst[0][tid] = (_Float16)h_init[tid];
    {
        const int ss = tid >> 4, j0 = (tid & 15) << 2;
        f32x4 v = *(const f32x4*)(x + ((long)b * TT + ss) * DD + j0);
        half4 hv = {(_Float16)v[0], (_Float16)v[1], (_Float16)v[2], (_Float16)v[3]};
        *(half4*)&xch[0][ss][j0] = hv;
    }
    __syncthreads();

    const int ss_pf = tid >> 4, j0_pf = (tid & 15) << 2;

    for (int ci = 0; ci < 64; ++ci) {
        const int buf = ci & 1;
        const bool pf = (ci + 1) < 64;
        f32x4 g0;
        if (pf) {  // prefetch next 16-step x chunk (latency hidden over ~16 steps)
            g0 = *(const f32x4*)(x + ((long)b * TT + ((ci + 1) << 4) + ss_pf) * DD + j0_pf);
        }
#pragma unroll
        for (int s = 0; s < 16; ++s) {
            const int t = (ci << 4) + s;
            const int p = s & 1;
            // A fragments (x part from chunk buffer, h part from h stage);
            // address depends only on quad -> broadcast reads, conflict-free.
            const _Float16* xrow = &xch[buf][s][0];
            half8 a0 = *(const half8*)(xrow + quad * 8);
            half8 a1 = *(const half8*)(xrow + 32 + quad * 8);
            const _Float16* hrow = &hst[p][0];
            half8 a2 = *(const half8*)(hrow + quad * 8);
            half8 a3 = *(const half8*)(hrow + 32 + quad * 8);

            // bias enters as the C operand of the first MFMA of each chain.
            f32x4 acc0 = MFMA16(a0, bf[0][0], biasv[0]);
            f32x4 acc1 = MFMA16(a0, bf[1][0], biasv[1]);
            f32x4 acc2 = MFMA16(a0, bf[2][0], biasv[2]);
            f32x4 acc3 = MFMA16(a0, bf[3][0], biasv[3]);
            acc0 = MFMA16(a1, bf[0][1], acc0); acc1 = MFMA16(a1, bf[1][1], acc1);
            acc2 = MFMA16(a1, bf[2][1], acc2); acc3 = MFMA16(a1, bf[3][1], acc3);
            acc0 = MFMA16(a2, bf[0][2], acc0); acc1 = MFMA16(a2, bf[1][2], acc1);
            acc2 = MFMA16(a2, bf[2][2], acc2); acc3 = MFMA16(a2, bf[3][2], acc3);
            acc0 = MFMA16(a3, bf[0][3], acc0); acc1 = MFMA16(a3, bf[1][3], acc1);
            acc2 = MFMA16(a3, bf[2][3], acc2); acc3 = MFMA16(a3, bf[3][3], acc3);

            // activation: D reg0 -> (unit j) gate pre-acts (rows all identical)
            const float si = sigm(acc0[0]);
            const float sf = sigm(acc1[0]);
            const float tg = tanh_(acc2[0]);
            const float so = sigm(acc3[0]);
            c_state = sf * c_state + si * tg;
            const float hv = so * tanh_(c_state);
            if (writer) {
                hst[p ^ 1][j] = (_Float16)hv;
                y[((long)b * TT + t) * HH + j] = hv;
            }
            if (s == 15 && pf) {  // land prefetched chunk into the other buffer
                half4 h4 = {(_Float16)g0[0], (_Float16)g0[1],
                            (_Float16)g0[2], (_Float16)g0[3]};
                *(half4*)&xch[buf ^ 1][ss_pf][j0_pf] = h4;
            }
            __syncthreads();  // writes to hst[p^1]/xch visible before next reads
        }
    }
}

// ---------------------------------------------------------------------------
// Heads kernel: 2048 WGs x 256 threads; 256 (b,t)-rows per WG in 4 subtiles
// of 64. MFMA L1 (K=64,N=128) and L2 (K=32,N=128 block-diag per head), VALU
// dot-32 L3. Weights resident in registers (reused across 4 subtiles).
// (unchanged this round — next target)
// ---------------------------------------------------------------------------
__global__ __launch_bounds__(256) void heads_kernel(
    const float* __restrict__ y,
    const float* __restrict__ W1, const float* __restrict__ b1,
    const float* __restrict__ W2, const float* __restrict__ b2,
    const float* __restrict__ W3, const float* __restrict__ b3,
    float* __restrict__ outs)
{
    __shared__ alignas(16) _Float16 ybuf[64][72];    // stride 72 f16: 16B-aligned rows, 2-way banks
    __shared__ alignas(16) _Float16 h1buf[64][136];  // stride 136 f16
    __shared__ alignas(16) _Float16 h2buf[64][136];

    const int tid  = threadIdx.x;
    const int wave = tid >> 6;
    const int lane = tid & 63;
    const int col  = lane & 15;
    const int quad = lane >> 4;
    const int arow = (wave << 4) + col;  // this lane's A row within 64-row tile

    // W1 fragments: 8 N-tiles x 2 K-chunks. W1 flat (4*32=128 rows, 64 cols).
    half8 w1f[8][2]; float bias1[8];
#pragma unroll
    for (int nt = 0; nt < 8; ++nt) {
        const int n = nt * 16 + col;
        bias1[nt] = b1[n];
#pragma unroll
        for (int c = 0; c < 2; ++c) {
            const float* src = W1 + n * 64 + c * 32 + quad * 8;
            w1f[nt][c] = cvt8(*(const f32x4*)src, *(const f32x4*)(src + 4));
        }
    }
    // W2 fragments: 8 N-tiles (head = nt>>1), K=32 single chunk. Flat 128x32.
    half8 w2f[8]; float bias2[8];
#pragma unroll
    for (int nt = 0; nt < 8; ++nt) {
        const int n = nt * 16 + col;
        bias2[nt] = b2[n];
        const float* src = W2 + n * 32 + quad * 8;
        w2f[nt] = cvt8(*(const f32x4*)src, *(const f32x4*)(src + 4));
    }
    // W3 row for this thread's head (L3 done per (row,head) by one thread).
    const int hd3 = tid >> 6, row3 = tid & 63;
    float w3r[32];
#pragma unroll
    for (int i = 0; i < 32; i += 4) {
        f32x4 v = *(const f32x4*)(W3 + hd3 * 32 + i);
        w3r[i] = v[0]; w3r[i + 1] = v[1]; w3r[i + 2] = v[2]; w3r[i + 3] = v[3];
    }
    const float b3v = b3[hd3];

    for (int st = 0; st < 4; ++st) {
        const long base_row = (long)blockIdx.x * 256 + st * 64;
        // stage 64 rows of y (f32 -> f16 LDS)
#pragma unroll
        for (int jj = 0; jj < 4; ++jj) {
            const int off = (jj * 256 + tid) * 4;
            const int row = off >> 6, cc = off & 63;
            f32x4 v = *(const f32x4*)(y + base_row * 64 + off);
            half4 hv = {(_Float16)v[0], (_Float16)v[1], (_Float16)v[2], (_Float16)v[3]};
            *(half4*)&ybuf[row][cc] = hv;
        }
        __syncthreads();

        // L1: h1 = relu(y @ W1^T + b1)
        half8 a0 = *(const half8*)&ybuf[arow][quad * 8];
        half8 a1 = *(const half8*)&ybuf[arow][32 + quad * 8];
#pragma unroll
        for (int nt = 0; nt < 8; ++nt) {
            f32x4 acc = {bias1[nt], bias1[nt], bias1[nt], bias1[nt]};
            acc = MFMA16(a0, w1f[nt][0], acc);
            acc = MFMA16(a1, w1f[nt][1], acc);
#pragma unroll
            for (int r = 0; r < 4; ++r) {
                float v = acc[r] > 0.0f ? acc[r] : 0.0f;
                h1buf[(wave << 4) + (quad << 2) + r][nt * 16 + col] = (_Float16)v;
            }
        }
        __syncthreads();

        // L2: h2 = relu(h1 @ W2^T + b2), block-diagonal per head
        half8 ah[4];
#pragma unroll
        for (int hd = 0; hd < 4; ++hd)
            ah[hd] = *(const half8*)&h1buf[arow][hd * 32 + quad * 8];
#pragma unroll
        for (int nt = 0; nt < 8; ++nt) {
            f32x4 acc = {bias2[nt], bias2[nt], bias2[nt], bias2[nt]};
            acc = MFMA16(ah[nt >> 1], w2f[nt], acc);
#pragma unroll
            for (int r = 0; r < 4; ++r) {
                float v = acc[r] > 0.0f ? acc[r] : 0.0f;
                h2buf[(wave << 4) + (quad << 2) + r][nt * 16 + col] = (_Float16)v;
            }
        }
        __syncthreads();

        // L3: out[hd][row] = h2[row][hd*32 .. +32] . W3[hd] + b3[hd]
        float acc = b3v;
#pragma unroll
        for (int c = 0; c < 4; ++c) {
            half8 v = *(const half8*)&h2buf[row3][hd3 * 32 + c * 8];
#pragma unroll
            for (int u = 0; u < 8; ++u)
                acc = fmaf((float)v[u], w3r[c * 8 + u], acc);
        }
        outs[(long)hd3 * BT + base_row + row3] = acc;
        __syncthreads();  // before next subtile overwrites the LDS buffers
    }
}

extern "C" void kernel_launch(void* const* d_in, const int* in_sizes, int n_in,
                              void* d_out, int out_size, void* d_ws, size_t ws_size,
                              hipStream_t stream) {
    (void)in_sizes; (void)n_in; (void)out_size; (void)d_ws; (void)ws_size;
    const float* x      = (const float*)d_in[0];
    const float* h_init = (const float*)d_in[1];
    const float* c_init = (const float*)d_in[2];
    const float* W_ih   = (const float*)d_in[3];
    const float* W_hh   = (const float*)d_in[4];
    const float* b_ih   = (const float*)d_in[5];
    const float* b_hh   = (const float*)d_in[6];
    const float* W1     = (const float*)d_in[7];
    const float* b1     = (const float*)d_in[8];
    const float* W2     = (const float*)d_in[9];
    const float* b2     = (const float*)d_in[10];
    const float* W3     = (const float*)d_in[11];
    const float* b3     = (const float*)d_in[12];
    float* y    = (float*)d_out;
    float* outs = y + Y_SIZE;

    lstm_kernel<<<dim3(512), dim3(256), 0, stream>>>(x, h_init, c_init, W_ih, W_hh,
                                                     b_ih, b_hh, y);
    heads_kernel<<<dim3(2048), dim3(256), 0, stream>>>(y, W1, b1, W2, b2, W3, b3, outs);
}

// Round 2
// 563.946 us; speedup vs baseline: 1.2677x; 1.2677x over previous
//
#include <hip/hip_runtime.h>

// Problem dims (fixed).
#define BB 512
#define TT 1024
#define DD 64
#define HH 64
#define G4 256          // 4*H gates
#define RR 4
#define MHH 32
#define BT (BB * TT)    // 524288
#define Y_SIZE (BB * TT * HH)  // 33554432

typedef _Float16 half8 __attribute__((ext_vector_type(8)));
typedef _Float16 half4 __attribute__((ext_vector_type(4)));
typedef float f32x4 __attribute__((ext_vector_type(4)));

#define MFMA16(a, b, c) __builtin_amdgcn_mfma_f32_16x16x32_f16((a), (b), (c), 0, 0, 0)

// Raw workgroup barrier that drains ONLY lgkmcnt (LDS), leaving global
// stores / prefetch loads in flight. __syncthreads() would emit
// s_waitcnt vmcnt(0) expcnt(0) lgkmcnt(0) and stall ~200-400 cyc per step
// on y-store completion that no consumer in this dispatch needs.
// All cross-wave communication in both kernels is LDS-only (lgkm-tracked).
__device__ __forceinline__ void wg_barrier_lds() {
    asm volatile("s_waitcnt lgkmcnt(0)" ::: "memory");
    __builtin_amdgcn_s_barrier();
    asm volatile("" ::: "memory");
}

// sigmoid(x) = 1/(1+e^-x); stable at both ends (exp->inf => rcp->0).
__device__ __forceinline__ float sigm(float x) {
    return __builtin_amdgcn_rcpf(1.0f + __expf(-x));
}
// tanh(x) = 1 - 2/(1+e^{2x}); stable at both ends.
__device__ __forceinline__ float tanh_(float x) {
    return 1.0f - 2.0f * __builtin_amdgcn_rcpf(1.0f + __expf(2.0f * x));
}

__device__ __forceinline__ half8 cvt8(f32x4 a, f32x4 b) {
    half8 h;
    h[0] = (_Float16)a[0]; h[1] = (_Float16)a[1];
    h[2] = (_Float16)a[2]; h[3] = (_Float16)a[3];
    h[4] = (_Float16)b[0]; h[5] = (_Float16)b[1];
    h[6] = (_Float16)b[2]; h[7] = (_Float16)b[3];
    return h;
}

// ---------------------------------------------------------------------------
// LSTM kernel: 256 WGs (one per 2 batch rows), 256 threads (4 waves).
// [R1 post-mortem: 512 WGs x 1 row regressed 330->496us — replicated-A issue
//  cost (~270 VALU + MFMA cyc/step/WG) x 2 WGs/CU exceeds the 774-cyc latency
//  envelope; the step became pipe-bound on duplicate work. Keep 1 WG/CU.]
// Per step: gates(2x256) = [x_t ; h](2x128,f16) @ Wcat^T via mfma 16x16x32.
// A-matrix replication: rows 0-7 = batch0, rows 8-15 = batch1, so D reg0 of
// every lane holds a valid gate (batch = lane>>5, col = lane&15). Wave w owns
// N-tiles {w, w+4, w+8, w+12} => lanes own units j = 16w + (lane&15) for all
// four gate groups i,f,g,o -> in-wave activation, no gate LDS round trip.
// h double-buffered in LDS => ONE raw (lgkm-only) barrier per step.
// ---------------------------------------------------------------------------
__global__ __launch_bounds__(256) void lstm_kernel(
    const float* __restrict__ x, const float* __restrict__ h_init,
    const float* __restrict__ c_init, const float* __restrict__ W_ih,
    const float* __restrict__ W_hh, const float* __restrict__ b_ih,
    const float* __restrict__ b_hh, float* __restrict__ y)
{
    __shared__ alignas(16) _Float16 xch[2][16][2][DD];  // x chunks, f16, dbuf
    __shared__ alignas(16) _Float16 hst[2][2][HH];      // h stage, dbuf

    const int tid  = threadIdx.x;
    const int wave = tid >> 6;
    const int lane = tid & 63;
    const int col  = lane & 15;
    const int quad = lane >> 4;
    const int sel  = (lane >> 3) & 1;       // which batch row this lane feeds as A
    const int r_act = lane >> 5;            // batch row this lane's unit belongs to
    const int j    = (wave << 4) + col;     // hidden unit index [0,64)
    const bool writer = ((lane >> 4) & 1) == 0;  // quads 1,3 are duplicates

    const int b0 = blockIdx.x * 2;

    // ---- resident weight fragments: B[k][n] = Wcat[n][k] (f16) ----
    // n = 64*G + j ; k chunks: 0,1 -> W_ih, 2,3 -> W_hh
    half8 bf[4][4];
    f32x4 biasv[4];
#pragma unroll
    for (int G = 0; G < 4; ++G) {
        const int n = (G << 6) + j;
        const float bs = b_ih[n] + b_hh[n];
        biasv[G][0] = bs; biasv[G][1] = bs; biasv[G][2] = bs; biasv[G][3] = bs;
#pragma unroll
        for (int c = 0; c < 4; ++c) {
            const float* src = (c < 2) ? (W_ih + n * DD + c * 32 + quad * 8)
                                       : (W_hh + n * HH + (c - 2) * 32 + quad * 8);
            f32x4 w0 = *(const f32x4*)src;
            f32x4 w1 = *(const f32x4*)(src + 4);
            bf[G][c] = cvt8(w0, w1);
        }
    }

    float c_state = c_init[j];

    // ---- init h stage (buffer 0) + first x chunk ----
    if (tid < 128) {
        const int rr = tid >> 6, jj = tid & 63;
        hst[0][rr][jj] = (_Float16)h_init[jj];
    }
    {
        const int ss = tid >> 4, rr = (tid >> 3) & 1, j0 = (tid & 7) << 3;
        const float* src = x + ((b0 + rr) * TT + ss) * DD + j0;
        f32x4 g0 = *(const f32x4*)src;
        f32x4 g1 = *(const f32x4*)(src + 4);
        *(half8*)&xch[0][ss][rr][j0] = cvt8(g0, g1);
    }
    wg_barrier_lds();

    const int ss_pf = tid >> 4, rr_pf = (tid >> 3) & 1, j0_pf = (tid & 7) << 3;

    for (int ci = 0; ci < 64; ++ci) {
        const int buf = ci & 1;
        const bool pf = (ci + 1) < 64;
        f32x4 g0, g1;
        if (pf) {  // prefetch next 16-step x chunk (latency hidden over ~16 steps)
            const float* src = x + ((b0 + rr_pf) * TT + ((ci + 1) << 4) + ss_pf) * DD + j0_pf;
            g0 = *(const f32x4*)src;
            g1 = *(const f32x4*)(src + 4);
        }
#pragma unroll
        for (int s = 0; s < 16; ++s) {
            const int t = (ci << 4) + s;
            const int p = s & 1;
            // A fragments (x part from chunk buffer, h part from h stage)
            const _Float16* xrow = &xch[buf][s][sel][0];
            half8 a0 = *(const half8*)(xrow + quad * 8);
            half8 a1 = *(const half8*)(xrow + 32 + quad * 8);
            const _Float16* hrow = &hst[p][sel][0];
            half8 a2 = *(const half8*)(hrow + quad * 8);
            half8 a3 = *(const half8*)(hrow + 32 + quad * 8);

            // bias enters as the C operand of the first MFMA of each chain;
            // x-part MFMAs first so only the last two depend on the fresh h.
            f32x4 acc0 = MFMA16(a0, bf[0][0], biasv[0]);
            f32x4 acc1 = MFMA16(a0, bf[1][0], biasv[1]);
            f32x4 acc2 = MFMA16(a0, bf[2][0], biasv[2]);
            f32x4 acc3 = MFMA16(a0, bf[3][0], biasv[3]);
            acc0 = MFMA16(a1, bf[0][1], acc0); acc1 = MFMA16(a1, bf[1][1], acc1);
            acc2 = MFMA16(a1, bf[2][1], acc2); acc3 = MFMA16(a1, bf[3][1], acc3);
            acc0 = MFMA16(a2, bf[0][2], acc0); acc1 = MFMA16(a2, bf[1][2], acc1);
            acc2 = MFMA16(a2, bf[2][2], acc2); acc3 = MFMA16(a2, bf[3][2], acc3);
            acc0 = MFMA16(a3, bf[0][3], acc0); acc1 = MFMA16(a3, bf[1][3], acc1);
            acc2 = MFMA16(a3, bf[2][3], acc2); acc3 = MFMA16(a3, bf[3][3], acc3);

            // activation: D reg0 -> (batch r_act, unit j) gate pre-acts
            const float si = sigm(acc0[0]);
            const float sf = sigm(acc1[0]);
            const float tg = tanh_(acc2[0]);
            const float so = sigm(acc3[0]);
            c_state = sf * c_state + si * tg;
            const float hv = so * tanh_(c_state);
            if (writer) {
                hst[p ^ 1][r_act][j] = (_Float16)hv;
                y[((b0 + r_act) * TT + t) * HH + j] = hv;  // left in flight across barrier
            }
            if (s == 15 && pf) {  // land prefetched chunk into the other buffer
                *(half8*)&xch[buf ^ 1][ss_pf][rr_pf][j0_pf] = cvt8(g0, g1);
            }
            wg_barrier_lds();  // lgkm-only: hst/xch visible; y stores NOT drained
        }
    }
}

// ---------------------------------------------------------------------------
// Heads kernel: 2048 WGs x 256 threads; 256 (b,t)-rows per WG in 4 subtiles
// of 64. MFMA L1 (K=64,N=128) and L2 (K=32,N=128 block-diag per head), VALU
// dot-32 L3. Weights resident in registers (reused across 4 subtiles).
// Barriers are raw lgkm-only (no vmcnt drain of y-stage loads / outs stores).
// ---------------------------------------------------------------------------
__global__ __launch_bounds__(256) void heads_kernel(
    const float* __restrict__ y,
    const float* __restrict__ W1, const float* __restrict__ b1,
    const float* __restrict__ W2, const float* __restrict__ b2,
    const float* __restrict__ W3, const float* __restrict__ b3,
    float* __restrict__ outs)
{
    __shared__ alignas(16) _Float16 ybuf[64][72];    // stride 72 f16: 16B-aligned rows, 2-way banks
    __shared__ alignas(16) _Float16 h1buf[64][136];  // stride 136 f16
    __shared__ alignas(16) _Float16 h2buf[64][136];

    const int tid  = threadIdx.x;
    const int wave = tid >> 6;
    const int lane = tid & 63;
    const int col  = lane & 15;
    const int quad = lane >> 4;
    const int arow = (wave << 4) + col;  // this lane's A row within 64-row tile

    // W1 fragments: 8 N-tiles x 2 K-chunks. W1 flat (4*32=128 rows, 64 cols).
    half8 w1f[8][2]; float bias1[8];
#pragma unroll
    for (int nt = 0; nt < 8; ++nt) {
        const int n = nt * 16 + col;
        bias1[nt] = b1[n];
#pragma unroll
        for (int c = 0; c < 2; ++c) {
            const float* src = W1 + n * 64 + c * 32 + quad * 8;
            w1f[nt][c] = cvt8(*(const f32x4*)src, *(const f32x4*)(src + 4));
        }
    }
    // W2 fragments: 8 N-tiles (head = nt>>1), K=32 single chunk. Flat 128x32.
    half8 w2f[8]; float bias2[8];
#pragma unroll
    for (int nt = 0; nt < 8; ++nt) {
        const int n = nt * 16 + col;
        bias2[nt] = b2[n];
        const float* src = W2 + n * 32 + quad * 8;
        w2f[nt] = cvt8(*(const f32x4*)src, *(const f32x4*)(src + 4));
    }
    // W3 row for this thread's head (L3 done per (row,head) by one thread).
    const int hd3 = tid >> 6, row3 = tid & 63;
    float w3r[32];
#pragma unroll
    for (int i = 0; i < 32; i += 4) {
        f32x4 v = *(const f32x4*)(W3 + hd3 * 32 + i);
        w3r[i] = v[0]; w3r[i + 1] = v[1]; w3r[i + 2] = v[2]; w3r[i + 3] = v[3];
    }
    const float b3v = b3[hd3];

    for (int st = 0; st < 4; ++st) {
        const long base_row = (long)blockIdx.x * 256 + st * 64;
        // stage 64 rows of y (f32 -> f16 LDS)
#pragma unroll
        for (int jj = 0; jj < 4; ++jj) {
            const int off = (jj * 256 + tid) * 4;
            const int row = off >> 6, cc = off & 63;
            f32x4 v = *(const f32x4*)(y + base_row * 64 + off);
            half4 hv = {(_Float16)v[0], (_Float16)v[1], (_Float16)v[2], (_Float16)v[3]};
            *(half4*)&ybuf[row][cc] = hv;
        }
        wg_barrier_lds();

        // L1: h1 = relu(y @ W1^T + b1)
        half8 a0 = *(const half8*)&ybuf[arow][quad * 8];
        half8 a1 = *(const half8*)&ybuf[arow][32 + quad * 8];
#pragma unroll
        for (int nt = 0; nt < 8; ++nt) {
            f32x4 acc = {bias1[nt], bias1[nt], bias1[nt], bias1[nt]};
            acc = MFMA16(a0, w1f[nt][0], acc);
            acc = MFMA16(a1, w1f[nt][1], acc);
#pragma unroll
            for (int r = 0; r < 4; ++r) {
                float v = acc[r] > 0.0f ? acc[r] : 0.0f;
                h1buf[(wave << 4) + (quad << 2) + r][nt * 16 + col] = (_Float16)v;
            }
        }
        wg_barrier_lds();

        // L2: h2 = relu(h1 @ W2^T + b2), block-diagonal per head
        half8 ah[4];
#pragma unroll
        for (int hd = 0; hd < 4; ++hd)
            ah[hd] = *(const half8*)&h1buf[arow][hd * 32 + quad * 8];
#pragma unroll
        for (int nt = 0; nt < 8; ++nt) {
            f32x4 acc = {bias2[nt], bias2[nt], bias2[nt], bias2[nt]};
            acc = MFMA16(ah[nt >> 1], w2f[nt], acc);
#pragma unroll
            for (int r = 0; r < 4; ++r) {
                float v = acc[r] > 0.0f ? acc[r] : 0.0f;
                h2buf[(wave << 4) + (quad << 2) + r][nt * 16 + col] = (_Float16)v;
            }
        }
        wg_barrier_lds();

        // L3: out[hd][row] = h2[row][hd*32 .. +32] . W3[hd] + b3[hd]
        float acc = b3v;
#pragma unroll
        for (int c = 0; c < 4; ++c) {
            half8 v = *(const half8*)&h2buf[row3][hd3 * 32 + c * 8];
#pragma unroll
            for (int u = 0; u < 8; ++u)
                acc = fmaf((float)v[u], w3r[c * 8 + u], acc);
        }
        outs[(long)hd3 * BT + base_row + row3] = acc;
        wg_barrier_lds();  // before next subtile overwrites the LDS buffers
    }
}

extern "C" void kernel_launch(void* const* d_in, const int* in_sizes, int n_in,
                              void* d_out, int out_size, void* d_ws, size_t ws_size,
                              hipStream_t stream) {
    (void)in_sizes; (void)n_in; (void)out_size; (void)d_ws; (void)ws_size;
    const float* x      = (const float*)d_in[0];
    const float* h_init = (const float*)d_in[1];
    const float* c_init = (const float*)d_in[2];
    const float* W_ih   = (const float*)d_in[3];
    const float* W_hh   = (const float*)d_in[4];
    const float* b_ih   = (const float*)d_in[5];
    const float* b_hh   = (const float*)d_in[6];
    const float* W1     = (const float*)d_in[7];
    const float* b1     = (const float*)d_in[8];
    const float* W2     = (const float*)d_in[9];
    const float* b2     = (const float*)d_in[10];
    const float* W3     = (const float*)d_in[11];
    const float* b3     = (const float*)d_in[12];
    float* y    = (float*)d_out;
    float* outs = y + Y_SIZE;

    lstm_kernel<<<dim3(256), dim3(256), 0, stream>>>(x, h_init, c_init, W_ih, W_hh,
                                                     b_ih, b_hh, y);
    heads_kernel<<<dim3(2048), dim3(256), 0, stream>>>(y, W1, b1, W2, b2, W3, b3, outs);
}

// Round 3
// 563.672 us; speedup vs baseline: 1.2683x; 1.0005x over previous
//
#include <hip/hip_runtime.h>

// Problem dims (fixed).
#define BB 512
#define TT 1024
#define DD 64
#define HH 64
#define G4 256          // 4*H gates
#define RR 4
#define MHH 32
#define BT (BB * TT)    // 524288
#define Y_SIZE (BB * TT * HH)  // 33554432

typedef _Float16 half8 __attribute__((ext_vector_type(8)));
typedef _Float16 half4 __attribute__((ext_vector_type(4)));
typedef float f32x4 __attribute__((ext_vector_type(4)));

#define MFMA16(a, b, c) __builtin_amdgcn_mfma_f32_16x16x32_f16((a), (b), (c), 0, 0, 0)

// Raw workgroup barrier that drains ONLY lgkmcnt (LDS), leaving global
// stores / prefetch loads in flight (R2: worth ~2% on lstm; kept).
__device__ __forceinline__ void wg_barrier_lds() {
    asm volatile("s_waitcnt lgkmcnt(0)" ::: "memory");
    __builtin_amdgcn_s_barrier();
    asm volatile("" ::: "memory");
}

// sigmoid(x) = 1/(1+e^-x); stable at both ends (exp->inf => rcp->0).
__device__ __forceinline__ float sigm(float x) {
    return __builtin_amdgcn_rcpf(1.0f + __expf(-x));
}
// tanh(x) = 1 - 2/(1+e^{2x}); stable at both ends.
__device__ __forceinline__ float tanh_(float x) {
    return 1.0f - 2.0f * __builtin_amdgcn_rcpf(1.0f + __expf(2.0f * x));
}

__device__ __forceinline__ half8 cvt8(f32x4 a, f32x4 b) {
    half8 h;
    h[0] = (_Float16)a[0]; h[1] = (_Float16)a[1];
    h[2] = (_Float16)a[2]; h[3] = (_Float16)a[3];
    h[4] = (_Float16)b[0]; h[5] = (_Float16)b[1];
    h[6] = (_Float16)b[2]; h[7] = (_Float16)b[3];
    return h;
}

// ---------------------------------------------------------------------------
// LSTM kernel: 256 WGs (one per 2 batch rows), 256 threads (4 waves).
// [R1: 512 WGs x 1 row regressed (replicated-A issue cost x 2 WGs/CU) — keep
//  1 WG/CU. R2: lgkm-only barrier +2%. R3: software-pipeline the x-part.]
// Step t critical path was a 4-deep MFMA chain (bias->x0->x1->h0->h1). Now
// xacc(t+1) = bias + x_{t+1} @ W_ih^T is computed during step t's activation
// phase (matrix pipe overlaps VALU, m114), so step t's serial chain is only
// h-read -> 2-deep h-MFMA -> activation -> h-write -> barrier.
// Chunk landing moved to s==14 so s==15 can pre-read next chunk's row 0.
// ---------------------------------------------------------------------------
__global__ __launch_bounds__(256) void lstm_kernel(
    const float* __restrict__ x, const float* __restrict__ h_init,
    const float* __restrict__ c_init, const float* __restrict__ W_ih,
    const float* __restrict__ W_hh, const float* __restrict__ b_ih,
    const float* __restrict__ b_hh, float* __restrict__ y)
{
    __shared__ alignas(16) _Float16 xch[2][16][2][DD];  // x chunks, f16, dbuf
    __shared__ alignas(16) _Float16 hst[2][2][HH];      // h stage, dbuf

    const int tid  = threadIdx.x;
    const int wave = tid >> 6;
    const int lane = tid & 63;
    const int col  = lane & 15;
    const int quad = lane >> 4;
    const int sel  = (lane >> 3) & 1;       // which batch row this lane feeds as A
    const int r_act = lane >> 5;            // batch row this lane's unit belongs to
    const int j    = (wave << 4) + col;     // hidden unit index [0,64)
    const bool writer = ((lane >> 4) & 1) == 0;  // quads 1,3 are duplicates

    const int b0 = blockIdx.x * 2;

    // ---- resident weight fragments: B[k][n] = Wcat[n][k] (f16) ----
    // n = 64*G + j ; k chunks: 0,1 -> W_ih, 2,3 -> W_hh
    half8 bf[4][4];
    f32x4 biasv[4];
#pragma unroll
    for (int G = 0; G < 4; ++G) {
        const int n = (G << 6) + j;
        const float bs = b_ih[n] + b_hh[n];
        biasv[G][0] = bs; biasv[G][1] = bs; biasv[G][2] = bs; biasv[G][3] = bs;
#pragma unroll
        for (int c = 0; c < 4; ++c) {
            const float* src = (c < 2) ? (W_ih + n * DD + c * 32 + quad * 8)
                                       : (W_hh + n * HH + (c - 2) * 32 + quad * 8);
            f32x4 w0 = *(const f32x4*)src;
            f32x4 w1 = *(const f32x4*)(src + 4);
            bf[G][c] = cvt8(w0, w1);
        }
    }

    float c_state = c_init[j];

    // ---- init h stage (buffer 0) + first x chunk ----
    if (tid < 128) {
        const int rr = tid >> 6, jj = tid & 63;
        hst[0][rr][jj] = (_Float16)h_init[jj];
    }
    {
        const int ss = tid >> 4, rr = (tid >> 3) & 1, j0 = (tid & 7) << 3;
        const float* src = x + ((b0 + rr) * TT + ss) * DD + j0;
        f32x4 g0 = *(const f32x4*)src;
        f32x4 g1 = *(const f32x4*)(src + 4);
        *(half8*)&xch[0][ss][rr][j0] = cvt8(g0, g1);
    }
    wg_barrier_lds();

    const int ss_pf = tid >> 4, rr_pf = (tid >> 3) & 1, j0_pf = (tid & 7) << 3;

    // ---- x-part pipeline prologue: xacc for t=0 ----
    f32x4 xacc0, xacc1, xacc2, xacc3;
    {
        const _Float16* xrow = &xch[0][0][sel][0];
        half8 a0 = *(const half8*)(xrow + quad * 8);
        half8 a1 = *(const half8*)(xrow + 32 + quad * 8);
        xacc0 = MFMA16(a0, bf[0][0], biasv[0]); xacc0 = MFMA16(a1, bf[0][1], xacc0);
        xacc1 = MFMA16(a0, bf[1][0], biasv[1]); xacc1 = MFMA16(a1, bf[1][1], xacc1);
        xacc2 = MFMA16(a0, bf[2][0], biasv[2]); xacc2 = MFMA16(a1, bf[2][1], xacc2);
        xacc3 = MFMA16(a0, bf[3][0], biasv[3]); xacc3 = MFMA16(a1, bf[3][1], xacc3);
    }

    for (int ci = 0; ci < 64; ++ci) {
        const int buf = ci & 1;
        const bool pf = (ci + 1) < 64;
        f32x4 g0, g1;
        if (pf) {  // prefetch next 16-step x chunk (lands at s==14)
            const float* src = x + ((b0 + rr_pf) * TT + ((ci + 1) << 4) + ss_pf) * DD + j0_pf;
            g0 = *(const f32x4*)src;
            g1 = *(const f32x4*)(src + 4);
        }
#pragma unroll
        for (int s = 0; s < 16; ++s) {
            const int t = (ci << 4) + s;
            const int p = s & 1;

            // h-part: 2-deep MFMA chain on top of the precomputed xacc.
            const _Float16* hrow = &hst[p][sel][0];
            half8 a2 = *(const half8*)(hrow + quad * 8);
            half8 a3 = *(const half8*)(hrow + 32 + quad * 8);
            f32x4 acc0 = MFMA16(a2, bf[0][2], xacc0); 
            f32x4 acc1 = MFMA16(a2, bf[1][2], xacc1);
            f32x4 acc2 = MFMA16(a2, bf[2][2], xacc2);
            f32x4 acc3 = MFMA16(a2, bf[3][2], xacc3);
            acc0 = MFMA16(a3, bf[0][3], acc0); acc1 = MFMA16(a3, bf[1][3], acc1);
            acc2 = MFMA16(a3, bf[2][3], acc2); acc3 = MFMA16(a3, bf[3][3], acc3);

            // next step's x-part: independent of h(t); issues on the matrix
            // pipe while the VALU runs the activation below.
            if (t < TT - 1) {
                const _Float16* nx = (s < 15) ? &xch[buf][s + 1][sel][0]
                                              : &xch[buf ^ 1][0][sel][0];
                half8 a0 = *(const half8*)(nx + quad * 8);
                half8 a1 = *(const half8*)(nx + 32 + quad * 8);
                xacc0 = MFMA16(a0, bf[0][0], biasv[0]); xacc0 = MFMA16(a1, bf[0][1], xacc0);
                xacc1 = MFMA16(a0, bf[1][0], biasv[1]); xacc1 = MFMA16(a1, bf[1][1], xacc1);
                xacc2 = MFMA16(a0, bf[2][0], biasv[2]); xacc2 = MFMA16(a1, bf[2][1], xacc2);
                xacc3 = MFMA16(a0, bf[3][0], biasv[3]); xacc3 = MFMA16(a1, bf[3][1], xacc3);
            }

            // activation: D reg0 -> (batch r_act, unit j) gate pre-acts
            const float si = sigm(acc0[0]);
            const float sf = sigm(acc1[0]);
            const float tg = tanh_(acc2[0]);
            const float so = sigm(acc3[0]);
            c_state = sf * c_state + si * tg;
            const float hv = so * tanh_(c_state);
            if (writer) {
                hst[p ^ 1][r_act][j] = (_Float16)hv;
                y[((b0 + r_act) * TT + t) * HH + j] = hv;  // in flight across barrier
            }
            if (s == 14 && pf) {  // land prefetched chunk; published by s14 barrier
                *(half8*)&xch[buf ^ 1][ss_pf][rr_pf][j0_pf] = cvt8(g0, g1);
            }
            wg_barrier_lds();  // lgkm-only: hst/xch visible; y stores NOT drained
        }
    }
}

// ---------------------------------------------------------------------------
// Heads kernel: unchanged from R2 (isolating the lstm delta; heads counters
// should surface in top-5 next round — it's ~240us vs a ~25us memory floor).
// ---------------------------------------------------------------------------
__global__ __launch_bounds__(256) void heads_kernel(
    const float* __restrict__ y,
    const float* __restrict__ W1, const float* __restrict__ b1,
    const float* __restrict__ W2, const float* __restrict__ b2,
    const float* __restrict__ W3, const float* __restrict__ b3,
    float* __restrict__ outs)
{
    __shared__ alignas(16) _Float16 ybuf[64][72];    // stride 72 f16: 16B-aligned rows, 2-way banks
    __shared__ alignas(16) _Float16 h1buf[64][136];  // stride 136 f16
    __shared__ alignas(16) _Float16 h2buf[64][136];

    const int tid  = threadIdx.x;
    const int wave = tid >> 6;
    const int lane = tid & 63;
    const int col  = lane & 15;
    const int quad = lane >> 4;
    const int arow = (wave << 4) + col;  // this lane's A row within 64-row tile

    // W1 fragments: 8 N-tiles x 2 K-chunks. W1 flat (4*32=128 rows, 64 cols).
    half8 w1f[8][2]; float bias1[8];
#pragma unroll
    for (int nt = 0; nt < 8; ++nt) {
        const int n = nt * 16 + col;
        bias1[nt] = b1[n];
#pragma unroll
        for (int c = 0; c < 2; ++c) {
            const float* src = W1 + n * 64 + c * 32 + quad * 8;
            w1f[nt][c] = cvt8(*(const f32x4*)src, *(const f32x4*)(src + 4));
        }
    }
    // W2 fragments: 8 N-tiles (head = nt>>1), K=32 single chunk. Flat 128x32.
    half8 w2f[8]; float bias2[8];
#pragma unroll
    for (int nt = 0; nt < 8; ++nt) {
        const int n = nt * 16 + col;
        bias2[nt] = b2[n];
        const float* src = W2 + n * 32 + quad * 8;
        w2f[nt] = cvt8(*(const f32x4*)src, *(const f32x4*)(src + 4));
    }
    // W3 row for this thread's head (L3 done per (row,head) by one thread).
    const int hd3 = tid >> 6, row3 = tid & 63;
    float w3r[32];
#pragma unroll
    for (int i = 0; i < 32; i += 4) {
        f32x4 v = *(const f32x4*)(W3 + hd3 * 32 + i);
        w3r[i] = v[0]; w3r[i + 1] = v[1]; w3r[i + 2] = v[2]; w3r[i + 3] = v[3];
    }
    const float b3v = b3[hd3];

    for (int st = 0; st < 4; ++st) {
        const long base_row = (long)blockIdx.x * 256 + st * 64;
        // stage 64 rows of y (f32 -> f16 LDS)
#pragma unroll
        for (int jj = 0; jj < 4; ++jj) {
            const int off = (jj * 256 + tid) * 4;
            const int row = off >> 6, cc = off & 63;
            f32x4 v = *(const f32x4*)(y + base_row * 64 + off);
            half4 hv = {(_Float16)v[0], (_Float16)v[1], (_Float16)v[2], (_Float16)v[3]};
            *(half4*)&ybuf[row][cc] = hv;
        }
        wg_barrier_lds();

        // L1: h1 = relu(y @ W1^T + b1)
        half8 a0 = *(const half8*)&ybuf[arow][quad * 8];
        half8 a1 = *(const half8*)&ybuf[arow][32 + quad * 8];
#pragma unroll
        for (int nt = 0; nt < 8; ++nt) {
            f32x4 acc = {bias1[nt], bias1[nt], bias1[nt], bias1[nt]};
            acc = MFMA16(a0, w1f[nt][0], acc);
            acc = MFMA16(a1, w1f[nt][1], acc);
#pragma unroll
            for (int r = 0; r < 4; ++r) {
                float v = acc[r] > 0.0f ? acc[r] : 0.0f;
                h1buf[(wave << 4) + (quad << 2) + r][nt * 16 + col] = (_Float16)v;
            }
        }
        wg_barrier_lds();

        // L2: h2 = relu(h1 @ W2^T + b2), block-diagonal per head
        half8 ah[4];
#pragma unroll
        for (int hd = 0; hd < 4; ++hd)
            ah[hd] = *(const half8*)&h1buf[arow][hd * 32 + quad * 8];
#pragma unroll
        for (int nt = 0; nt < 8; ++nt) {
            f32x4 acc = {bias2[nt], bias2[nt], bias2[nt], bias2[nt]};
            acc = MFMA16(ah[nt >> 1], w2f[nt], acc);
#pragma unroll
            for (int r = 0; r < 4; ++r) {
                float v = acc[r] > 0.0f ? acc[r] : 0.0f;
                h2buf[(wave << 4) + (quad << 2) + r][nt * 16 + col] = (_Float16)v;
            }
        }
        wg_barrier_lds();

        // L3: out[hd][row] = h2[row][hd*32 .. +32] . W3[hd] + b3[hd]
        float acc = b3v;
#pragma unroll
        for (int c = 0; c < 4; ++c) {
            half8 v = *(const half8*)&h2buf[row3][hd3 * 32 + c * 8];
#pragma unroll
            for (int u = 0; u < 8; ++u)
                acc = fmaf((float)v[u], w3r[c * 8 + u], acc);
        }
        outs[(long)hd3 * BT + base_row + row3] = acc;
        wg_barrier_lds();  // before next subtile overwrites the LDS buffers
    }
}

extern "C" void kernel_launch(void* const* d_in, const int* in_sizes, int n_in,
                              void* d_out, int out_size, void* d_ws, size_t ws_size,
                              hipStream_t stream) {
    (void)in_sizes; (void)n_in; (void)out_size; (void)d_ws; (void)ws_size;
    const float* x      = (const float*)d_in[0];
    const float* h_init = (const float*)d_in[1];
    const float* c_init = (const float*)d_in[2];
    const float* W_ih   = (const float*)d_in[3];
    const float* W_hh   = (const float*)d_in[4];
    const float* b_ih   = (const float*)d_in[5];
    const float* b_hh   = (const float*)d_in[6];
    const float* W1     = (const float*)d_in[7];
    const float* b1     = (const float*)d_in[8];
    const float* W2     = (const float*)d_in[9];
    const float* b2     = (const float*)d_in[10];
    const float* W3     = (const float*)d_in[11];
    const float* b3     = (const float*)d_in[12];
    float* y    = (float*)d_out;
    float* outs = y + Y_SIZE;

    lstm_kernel<<<dim3(256), dim3(256), 0, stream>>>(x, h_init, c_init, W_ih, W_hh,
                                                     b_ih, b_hh, y);
    heads_kernel<<<dim3(2048), dim3(256), 0, stream>>>(y, W1, b1, W2, b2, W3, b3, outs);
}